// Round 2
// baseline (505.559 us; speedup 1.0000x reference)
//
#include <hip/hip_runtime.h>

// SparseAttention: x[8,8192,256] -> QKV proj (P folded into Q/K weights) ->
// block-diagonal (BS=8) softmax attention -> out[8,8192,256] fp32.
//
// prep: W_effT[768][256] bf16 (rows: Q 0..255 | K 256..511 | V 512..767) + beff[768].
// fused: persistent 512 blocks x 4 tiles of 32 tokens; double-buffered x->bf16 LDS
//   staging; swapped-operand MFMA GEMM (D[outcol][token]) so QKV->LDS is packed
//   b64 writes; per-(8-block, head) wave attention from swizzled LDS.

typedef __attribute__((ext_vector_type(8))) short bf16x8;
typedef __attribute__((ext_vector_type(4))) float f32x4;
typedef __attribute__((ext_vector_type(4))) unsigned int u32x4;
typedef __attribute__((ext_vector_type(2))) unsigned int u32x2;

__device__ __forceinline__ short f2bf(float f) {
  unsigned int u = __builtin_bit_cast(unsigned int, f);
  u = (u + 0x7FFFu + ((u >> 16) & 1u)) >> 16;  // RNE
  return (short)u;
}
__device__ __forceinline__ float bf2f(short s) {
  unsigned int u = ((unsigned int)(unsigned short)s) << 16;
  return __builtin_bit_cast(float, u);
}
__device__ __forceinline__ unsigned int cvtpk(float lo, float hi) {
  unsigned int r;
  asm("v_cvt_pk_bf16_f32 %0, %1, %2" : "=v"(r) : "v"(lo), "v"(hi));
  return r;
}
// LDS XOR swizzle, 16B granularity
__device__ __forceinline__ int swz(int r) { return ((r ^ (r >> 3)) & 7) << 4; }

// ---------------- prep: build W_effT (bf16) + beff ----------------
// blocks 0..63:  QK. b -> (m = b>>5, h = (b>>4)&1, i0 = (b&15)*8)
//   W_effT[m*256 + h*128 + i0+ii][e] = sum_d W_m[h*128+d][e] * P[d][i0+ii]
// blocks 64..79: V copy (bf16 cast), block 64 also writes V bias.
__global__ void prep(const float* __restrict__ Wq, const float* __restrict__ bq,
                     const float* __restrict__ Wk, const float* __restrict__ bk,
                     const float* __restrict__ Wv, const float* __restrict__ bv,
                     const float* __restrict__ P,
                     short* __restrict__ WT, float* __restrict__ beff) {
  __shared__ float Pl[128][8];
  const int b = blockIdx.x, tid = threadIdx.x;
  if (b < 64) {
    const int m = b >> 5, h = (b >> 4) & 1, i0 = (b & 15) * 8;
    // stage P[:, i0..i0+7] (128x8)
#pragma unroll
    for (int it = 0; it < 4; ++it) {
      const int idx = it * 256 + tid;
      Pl[idx >> 3][idx & 7] = P[(idx >> 3) * 128 + i0 + (idx & 7)];
    }
    __syncthreads();
    const float* __restrict__ W  = m ? Wk : Wq;
    const float* __restrict__ bb = m ? bk : bq;
    const int e = tid;  // 0..255
    float acc[8] = {0.f, 0.f, 0.f, 0.f, 0.f, 0.f, 0.f, 0.f};
#pragma unroll 4
    for (int d = 0; d < 128; ++d) {
      const float wv = W[(h * 128 + d) * 256 + e];
#pragma unroll
      for (int ii = 0; ii < 8; ++ii) acc[ii] += wv * Pl[d][ii];
    }
#pragma unroll
    for (int ii = 0; ii < 8; ++ii)
      WT[(m * 256 + h * 128 + i0 + ii) * 256 + e] = f2bf(acc[ii]);
    // bias: one wave, lanes (ii = l&7, dg = l>>3) partial over 16 d's, reduce
    if (tid < 64) {
      const int ii = tid & 7, dg = tid >> 3;
      float p = 0.f;
#pragma unroll
      for (int dd = 0; dd < 16; ++dd) {
        const int d = dg * 16 + dd;
        p += bb[h * 128 + d] * Pl[d][ii];
      }
      p += __shfl_xor(p, 8);
      p += __shfl_xor(p, 16);
      p += __shfl_xor(p, 32);
      if (tid < 8) beff[m * 256 + h * 128 + i0 + ii] = p;
    }
  } else {
    const int base = (b - 64) * 4096 + tid * 16;
    const float4* vp = (const float4*)(Wv + base);
    float4 f0 = vp[0], f1 = vp[1], f2 = vp[2], f3 = vp[3];
    u32x4 v0 = { cvtpk(f0.x, f0.y), cvtpk(f0.z, f0.w), cvtpk(f1.x, f1.y), cvtpk(f1.z, f1.w) };
    u32x4 v1 = { cvtpk(f2.x, f2.y), cvtpk(f2.z, f2.w), cvtpk(f3.x, f3.y), cvtpk(f3.z, f3.w) };
    *(u32x4*)(WT + 512 * 256 + base)     = v0;
    *(u32x4*)(WT + 512 * 256 + base + 8) = v1;
    if (b == 64) beff[512 + tid] = bv[tid];
  }
}

// ---------------- fused: QKV GEMM + block-diagonal attention ----------------
__global__ __launch_bounds__(512, 4)
void fused_qkv_attn(const float* __restrict__ x, const short* __restrict__ WT,
                    const float* __restrict__ beff, float* __restrict__ out) {
  // LDS: xaA/xaB = x tile [32][512B] bf16 (double buffer), qk = QKV [32][1536B]
  __shared__ __align__(16) char lds[81920];
  char* const xaA = lds;
  char* const xaB = lds + 16384;
  char* const qk  = lds + 32768;

  const int tid = threadIdx.x;
  const int w = tid >> 6, l = tid & 63;
  const int lrow = l & 15, lk = l >> 4;
  const int nb = w * 96;                       // this wave's 96 output cols
  const int sr = tid >> 4, skc = (tid & 15) * 16;  // staging row / col-chunk

  const long tile0 = (long)blockIdx.x * 4;

  // prologue: stage tile 0 -> xaA
  {
    const float4* xp = (const float4*)(x + (tile0 * 32 + sr) * 256 + skc);
    float4 f0 = xp[0], f1 = xp[1], f2 = xp[2], f3 = xp[3];
    u32x4 v0 = { cvtpk(f0.x, f0.y), cvtpk(f0.z, f0.w), cvtpk(f1.x, f1.y), cvtpk(f1.z, f1.w) };
    u32x4 v1 = { cvtpk(f2.x, f2.y), cvtpk(f2.z, f2.w), cvtpk(f3.x, f3.y), cvtpk(f3.z, f3.w) };
    *(u32x4*)(xaA + sr * 512 + ((skc * 2)      ^ swz(sr))) = v0;
    *(u32x4*)(xaA + sr * 512 + ((skc * 2 + 16) ^ swz(sr))) = v1;
  }

  for (int t = 0; t < 4; ++t) {
    char* const cur = (t & 1) ? xaB : xaA;
    char* const nxt = (t & 1) ? xaA : xaB;
    const long tok0 = (tile0 + t) * 32;
    __syncthreads();  // t=0: staging done; t>0: P4(t-1) done reading qk

    // issue next tile's x loads (consumed after GEMM -> latency hidden)
    float4 pf0, pf1, pf2, pf3;
    const bool pf = (t < 3);
    if (pf) {
      const float4* xp = (const float4*)(x + (tok0 + 32 + sr) * 256 + skc);
      pf0 = xp[0]; pf1 = xp[1]; pf2 = xp[2]; pf3 = xp[3];
    }

    // GEMM: D[outcol][token] = W_eff x-tile^T ; acc[mf][nf][r] -> col nb+nf*16+lk*4+r, tok mf*16+lrow
    f32x4 acc[2][6];
#pragma unroll
    for (int nf = 0; nf < 6; ++nf) {
      f32x4 bi = *(const f32x4*)(beff + nb + nf * 16 + lk * 4);
      acc[0][nf] = bi; acc[1][nf] = bi;
    }
#pragma unroll
    for (int ks = 0; ks < 8; ++ks) {
      const int kb = ks * 32;
      bf16x8 xf0 = *(const bf16x8*)(cur + lrow * 512        + ((kb * 2 + lk * 16) ^ swz(lrow)));
      bf16x8 xf1 = *(const bf16x8*)(cur + (16 + lrow) * 512 + ((kb * 2 + lk * 16) ^ swz(16 + lrow)));
#pragma unroll
      for (int nf = 0; nf < 6; ++nf) {
        bf16x8 wf = *(const bf16x8*)(WT + (nb + nf * 16 + lrow) * 256 + kb + lk * 8);
        acc[0][nf] = __builtin_amdgcn_mfma_f32_16x16x32_bf16(wf, xf0, acc[0][nf], 0, 0, 0);
        acc[1][nf] = __builtin_amdgcn_mfma_f32_16x16x32_bf16(wf, xf1, acc[1][nf], 0, 0, 0);
      }
    }

    // write prefetched x tile to the other buffer
    if (pf) {
      u32x4 v0 = { cvtpk(pf0.x, pf0.y), cvtpk(pf0.z, pf0.w), cvtpk(pf1.x, pf1.y), cvtpk(pf1.z, pf1.w) };
      u32x4 v1 = { cvtpk(pf2.x, pf2.y), cvtpk(pf2.z, pf2.w), cvtpk(pf3.x, pf3.y), cvtpk(pf3.z, pf3.w) };
      *(u32x4*)(nxt + sr * 512 + ((skc * 2)      ^ swz(sr))) = v0;
      *(u32x4*)(nxt + sr * 512 + ((skc * 2 + 16) ^ swz(sr))) = v1;
    }

    // P3: QKV -> LDS, packed b64 writes (4 consecutive cols per lane)
#pragma unroll
    for (int mf = 0; mf < 2; ++mf) {
      const int tok = mf * 16 + lrow;
#pragma unroll
      for (int nf = 0; nf < 6; ++nf) {
        u32x2 pw = { cvtpk(acc[mf][nf][0], acc[mf][nf][1]),
                     cvtpk(acc[mf][nf][2], acc[mf][nf][3]) };
        const int colb = (nb + nf * 16 + lk * 4) * 2;
        *(u32x2*)(qk + tok * 1536 + (colb ^ swz(tok))) = pw;
      }
    }
    __syncthreads();  // qk ready, nxt staged

    // P4: block-diagonal attention; one wave = one (8-block, head)
    {
      const int blk = w >> 1, h = w & 1;
      const int i = l >> 3, j = l & 7;      // query row, key col
      const int tq = blk * 8 + i, tk = blk * 8 + j;
      const int qc = h * 128, kcc = 256 + h * 128, vcc = 512 + h * 128;
      float s = 0.f;
#pragma unroll
      for (int dc = 0; dc < 16; ++dc) {
        bf16x8 qv = *(const bf16x8*)(qk + tq * 1536 + (((qc  + dc * 8) * 2) ^ swz(tq)));
        bf16x8 kv = *(const bf16x8*)(qk + tk * 1536 + (((kcc + dc * 8) * 2) ^ swz(tk)));
#pragma unroll
        for (int e = 0; e < 8; ++e) s += bf2f(qv[e]) * bf2f(kv[e]);
      }
      s *= 0.08838834764831843f;  // 1/sqrt(128)

      float mx = s;
      mx = fmaxf(mx, __shfl_xor(mx, 1, 8));
      mx = fmaxf(mx, __shfl_xor(mx, 2, 8));
      mx = fmaxf(mx, __shfl_xor(mx, 4, 8));
      const float p = __expf(s - mx);
      float sum = p;
      sum += __shfl_xor(sum, 1, 8);
      sum += __shfl_xor(sum, 2, 8);
      sum += __shfl_xor(sum, 4, 8);
      const float pn = p / sum;

      const int d0 = j * 16;
      float o[16];
#pragma unroll
      for (int c = 0; c < 16; ++c) o[c] = 0.f;
#pragma unroll
      for (int jj = 0; jj < 8; ++jj) {
        const float a = __shfl(pn, (l & 56) | jj, 64);  // attn[i][jj]
        const int tv = blk * 8 + jj;
        bf16x8 v0 = *(const bf16x8*)(qk + tv * 1536 + (((vcc + d0) * 2)     ^ swz(tv)));
        bf16x8 v1 = *(const bf16x8*)(qk + tv * 1536 + (((vcc + d0 + 8) * 2) ^ swz(tv)));
#pragma unroll
        for (int c = 0; c < 8; ++c) { o[c] += a * bf2f(v0[c]); o[8 + c] += a * bf2f(v1[c]); }
      }
      float4* op = (float4*)(out + (tok0 + tq) * 256 + h * 128 + d0);
      op[0] = (float4){o[0],  o[1],  o[2],  o[3]};
      op[1] = (float4){o[4],  o[5],  o[6],  o[7]};
      op[2] = (float4){o[8],  o[9],  o[10], o[11]};
      op[3] = (float4){o[12], o[13], o[14], o[15]};
    }
  }
}

extern "C" void kernel_launch(void* const* d_in, const int* in_sizes, int n_in,
                              void* d_out, int out_size, void* d_ws, size_t ws_size,
                              hipStream_t stream) {
  const float* x  = (const float*)d_in[0];
  const float* Wq = (const float*)d_in[1];
  const float* bq = (const float*)d_in[2];
  const float* Wk = (const float*)d_in[3];
  const float* bk = (const float*)d_in[4];
  const float* Wv = (const float*)d_in[5];
  const float* bv = (const float*)d_in[6];
  const float* P  = (const float*)d_in[7];
  float* out = (float*)d_out;

  short* WT   = (short*)d_ws;                          // 768*256 bf16 = 384 KB
  float* beff = (float*)((char*)d_ws + 768 * 256 * 2); // 768 fp32

  const int ntok = in_sizes[0] / 256;   // B*N = 65536
  prep<<<80, 256, 0, stream>>>(Wq, bq, Wk, bk, Wv, bv, P, WT, beff);
  fused_qkv_attn<<<ntok / (32 * 4), 512, 0, stream>>>(x, WT, beff, out);
}

// Round 6
// 229.413 us; speedup vs baseline: 2.2037x; 2.2037x over previous
//
#include <hip/hip_runtime.h>

// SparseAttention: x[8,8192,256] -> QKV proj (+ per-head P proj folded into
// weights) -> block-diagonal (BS=8) softmax attention -> out[8,8192,256] fp32.
//
// Kernel 1 (prep_weights): W_effT[768][256] bf16, c = [Q(0..255)|K(256..511)|V(512..767)]
//   Q/K cols have P folded in:  W_effT[h*128+i][e] = sum_d Wq[h*128+d][e] * P[d][i]
//   V cols are just Wv transposed. bias_eff likewise (zeros in practice).
// Kernel 2 (fused): per 32-token tile: stage x->bf16 LDS, MFMA GEMM vs W_effT
//   (L2-resident), QKV -> swizzled LDS, per-(8-block, head) attention per wave.

typedef __attribute__((ext_vector_type(8))) short bf16x8;
typedef __attribute__((ext_vector_type(4))) float f32x4;

__device__ __forceinline__ short f2bf(float f) {
  unsigned int u = __builtin_bit_cast(unsigned int, f);
  u = (u + 0x7FFFu + ((u >> 16) & 1u)) >> 16;  // RNE
  return (short)u;
}
__device__ __forceinline__ float bf2f(short s) {
  unsigned int u = ((unsigned int)(unsigned short)s) << 16;
  return __builtin_bit_cast(float, u);
}
// LDS XOR swizzle: distinct 16B slots for rows that would otherwise alias banks
__device__ __forceinline__ int swz(int r) { return ((r ^ (r >> 3)) & 7) << 4; }

__global__ void prep_weights(const float* __restrict__ Wq, const float* __restrict__ bq,
                             const float* __restrict__ Wk, const float* __restrict__ bk,
                             const float* __restrict__ Wv, const float* __restrict__ bv,
                             const float* __restrict__ P,
                             short* __restrict__ WT, float* __restrict__ beff) {
  const int c = blockIdx.x;   // 0..767 output column
  const int e = threadIdx.x;  // 0..255 input dim
  float acc = 0.f, bacc = 0.f;
  if (c < 512) {
    const float* W  = (c < 256) ? Wq : Wk;
    const float* bb = (c < 256) ? bq : bk;
    const int cc = c & 255;
    const int h = cc >> 7, i = cc & 127;
    for (int d = 0; d < 128; ++d) {
      const float p = P[d * 128 + i];
      acc += W[(h * 128 + d) * 256 + e] * p;   // coalesced over e
      if (e == 0) bacc += bb[h * 128 + d] * p;
    }
  } else {
    const int cc = c - 512;
    acc = Wv[cc * 256 + e];
    bacc = bv[cc];
  }
  WT[c * 256 + e] = f2bf(acc);
  if (e == 0) beff[c] = bacc;
}

__global__ __launch_bounds__(512, 4)
void fused_qkv_attn(const float* __restrict__ x, const short* __restrict__ WT,
                    const float* __restrict__ beff, float* __restrict__ out) {
  // LDS: xa = x tile [32 rows][512 B] (bf16, swizzled)
  //      qk = QKV tile [32 rows][1536 B] (bf16, swizzled); cols 0..255 Q, 256..511 K, 512..767 V
  __shared__ __align__(16) char lds[65536];
  char* const xa = lds;
  char* const qk = lds + 16384;

  const int tid = threadIdx.x;
  const long tok0 = (long)blockIdx.x * 32;

  // ---- Phase 1: stage x (32x256 fp32) -> bf16 LDS ----
  {
    const int r  = tid >> 4;          // token row 0..31
    const int kc = (tid & 15) * 16;   // element base
    const float4* xp = (const float4*)(x + (tok0 + r) * 256 + kc);
    float4 f0 = xp[0], f1 = xp[1], f2 = xp[2], f3 = xp[3];
    bf16x8 v0, v1;
    v0[0]=f2bf(f0.x); v0[1]=f2bf(f0.y); v0[2]=f2bf(f0.z); v0[3]=f2bf(f0.w);
    v0[4]=f2bf(f1.x); v0[5]=f2bf(f1.y); v0[6]=f2bf(f1.z); v0[7]=f2bf(f1.w);
    v1[0]=f2bf(f2.x); v1[1]=f2bf(f2.y); v1[2]=f2bf(f2.z); v1[3]=f2bf(f2.w);
    v1[4]=f2bf(f3.x); v1[5]=f2bf(f3.y); v1[6]=f2bf(f3.z); v1[7]=f2bf(f3.w);
    *(bf16x8*)(xa + r * 512 + ((kc * 2)       ^ swz(r))) = v0;
    *(bf16x8*)(xa + r * 512 + ((kc * 2 + 16)  ^ swz(r))) = v1;
  }
  __syncthreads();

  const int w = tid >> 6, l = tid & 63;
  const int lrow = l & 15, lk = l >> 4;
  const int nb = w * 96;  // this wave's 96 output cols

  // ---- Phase 2: GEMM (32 x 768 = x_tile @ W_effT^T), acc[mf][nf] ----
  f32x4 acc[2][6];
#pragma unroll
  for (int nf = 0; nf < 6; ++nf) {
    const float bv_ = beff[nb + nf * 16 + lrow];  // bias per output col
    acc[0][nf] = (f32x4){bv_, bv_, bv_, bv_};
    acc[1][nf] = acc[0][nf];
  }
#pragma unroll
  for (int ks = 0; ks < 8; ++ks) {
    const int kb = ks * 32;
    // A frags: A[row][k], row = l&15 (+16), k = kb + (l>>4)*8 + e
    bf16x8 a0 = *(const bf16x8*)(xa + lrow        * 512 + ((kb * 2 + lk * 16) ^ swz(lrow)));
    bf16x8 a1 = *(const bf16x8*)(xa + (16 + lrow) * 512 + ((kb * 2 + lk * 16) ^ swz(16 + lrow)));
#pragma unroll
    for (int nf = 0; nf < 6; ++nf) {
      // B frag: B[k][col], col = l&15; W_effT[col][k..k+8] contiguous 16B (L2-hot)
      const int col = nb + nf * 16 + lrow;
      bf16x8 b = *(const bf16x8*)(WT + col * 256 + kb + lk * 8);
      acc[0][nf] = __builtin_amdgcn_mfma_f32_16x16x32_bf16(a0, b, acc[0][nf], 0, 0, 0);
      acc[1][nf] = __builtin_amdgcn_mfma_f32_16x16x32_bf16(a1, b, acc[1][nf], 0, 0, 0);
    }
  }

  // ---- Phase 3: acc (C[row=(l>>4)*4+r][col=l&15]) -> qkv LDS as bf16 ----
#pragma unroll
  for (int mf = 0; mf < 2; ++mf)
#pragma unroll
    for (int nf = 0; nf < 6; ++nf)
#pragma unroll
      for (int r = 0; r < 4; ++r) {
        const int tok = mf * 16 + lk * 4 + r;
        const int c   = nb + nf * 16 + lrow;
        *(short*)(qk + tok * 1536 + ((c * 2) ^ swz(tok))) = f2bf(acc[mf][nf][r]);
      }
  __syncthreads();

  // ---- Phase 4: block-diagonal attention; one wave = one (8-block, head) ----
  {
    const int blk = w >> 1, h = w & 1;
    const int i = l >> 3, j = l & 7;      // query row, key col
    const int tq = blk * 8 + i, tk = blk * 8 + j;
    const int qc = h * 128, kcc = 256 + h * 128, vcc = 512 + h * 128;
    float s = 0.f;
#pragma unroll
    for (int dc = 0; dc < 16; ++dc) {
      bf16x8 qv = *(const bf16x8*)(qk + tq * 1536 + (((qc  + dc * 8) * 2) ^ swz(tq)));
      bf16x8 kv = *(const bf16x8*)(qk + tk * 1536 + (((kcc + dc * 8) * 2) ^ swz(tk)));
#pragma unroll
      for (int e = 0; e < 8; ++e) s += bf2f(qv[e]) * bf2f(kv[e]);
    }
    s *= 0.08838834764831843f;  // 1/sqrt(128)

    // softmax over the 8 keys (lanes i*8 .. i*8+7)
    float mx = s;
    mx = fmaxf(mx, __shfl_xor(mx, 1, 8));
    mx = fmaxf(mx, __shfl_xor(mx, 2, 8));
    mx = fmaxf(mx, __shfl_xor(mx, 4, 8));
    const float p = __expf(s - mx);
    float sum = p;
    sum += __shfl_xor(sum, 1, 8);
    sum += __shfl_xor(sum, 2, 8);
    sum += __shfl_xor(sum, 4, 8);
    const float pn = p / sum;

    // PV: lane handles (row i, d-chunk j*16 .. +15)
    const int d0 = j * 16;
    float o[16];
#pragma unroll
    for (int c = 0; c < 16; ++c) o[c] = 0.f;
#pragma unroll
    for (int jj = 0; jj < 8; ++jj) {
      const float a = __shfl(pn, (l & 56) | jj, 64);  // attn[i][jj]
      const int tv = blk * 8 + jj;
      bf16x8 v0 = *(const bf16x8*)(qk + tv * 1536 + (((vcc + d0) * 2)     ^ swz(tv)));
      bf16x8 v1 = *(const bf16x8*)(qk + tv * 1536 + (((vcc + d0 + 8) * 2) ^ swz(tv)));
#pragma unroll
      for (int c = 0; c < 8; ++c) { o[c] += a * bf2f(v0[c]); o[8 + c] += a * bf2f(v1[c]); }
    }
    float4* op = (float4*)(out + (tok0 + tq) * 256 + h * 128 + d0);
    op[0] = (float4){o[0],  o[1],  o[2],  o[3]};
    op[1] = (float4){o[4],  o[5],  o[6],  o[7]};
    op[2] = (float4){o[8],  o[9],  o[10], o[11]};
    op[3] = (float4){o[12], o[13], o[14], o[15]};
  }
}

extern "C" void kernel_launch(void* const* d_in, const int* in_sizes, int n_in,
                              void* d_out, int out_size, void* d_ws, size_t ws_size,
                              hipStream_t stream) {
  const float* x  = (const float*)d_in[0];
  const float* Wq = (const float*)d_in[1];
  const float* bq = (const float*)d_in[2];
  const float* Wk = (const float*)d_in[3];
  const float* bk = (const float*)d_in[4];
  const float* Wv = (const float*)d_in[5];
  const float* bv = (const float*)d_in[6];
  const float* P  = (const float*)d_in[7];
  float* out = (float*)d_out;

  short* WT   = (short*)d_ws;                          // 768*256 bf16 = 384 KB
  float* beff = (float*)((char*)d_ws + 768 * 256 * 2); // 768 fp32

  const int ntok = in_sizes[0] / 256;   // B*N = 65536
  prep_weights<<<768, 256, 0, stream>>>(Wq, bq, Wk, bk, Wv, bv, P, WT, beff);
  fused_qkv_attn<<<ntok / 32, 512, 0, stream>>>(x, WT, beff, out);
}